// Round 1
// baseline (1098.470 us; speedup 1.0000x reference)
//
#include <hip/hip_runtime.h>
#include <hip/hip_bf16.h>
#include <cstdint>
#include <cstddef>

// Problem constants (from reference): N=8, Lq=4096, C=768, H=8, P=4, D=96, 12^3 grid
#define N_B   8
#define LQ    4096
#define CDIM  768
#define HH    8
#define PPTS  4
#define DDIM  96
#define LIN   1728
#define NV    12

typedef unsigned short u16;

__device__ __forceinline__ float bf2f(u16 u) {
  unsigned x = ((unsigned)u) << 16;
  return __builtin_bit_cast(float, x);
}
__device__ __forceinline__ u16 f2bf(float f) {
  unsigned x = __builtin_bit_cast(unsigned, f);
  x += 0x7fffu + ((x >> 16) & 1u);   // round-to-nearest-even
  return (u16)(x >> 16);
}

__device__ __forceinline__ float ldA(const float* p) { return *p; }
__device__ __forceinline__ float ldA(const u16* p)   { return bf2f(*p); }
__device__ __forceinline__ void  stO(float* p, float v) { *p = v; }
__device__ __forceinline__ void  stO(u16* p, float v)   { *p = f2bf(v); }

// C[M x NCOLS] = A[M x 768] * B[768 x NCOLS] + bias
// BMODE 0: B0 is (768 x NCOLS) row-major, bias0[NCOLS].
// BMODE 1: NCOLS=128 concat: col<96 -> B0 (768x96)+bias0; col>=96 -> B1 (768x32)+bias1.
// Tile 64x64, K-step 16, 256 threads, 4x4 acc per thread. All dims divide evenly.
template<typename TA, typename TOUT, int BMODE, int NCOLS>
__global__ __launch_bounds__(256)
void gemm64(const TA* __restrict__ A, const float* __restrict__ B0,
            const float* __restrict__ B1, const float* __restrict__ bias0,
            const float* __restrict__ bias1, TOUT* __restrict__ out)
{
  __shared__ float As[16][64];   // As[k][m]
  __shared__ float Bs[16][64];   // Bs[k][n]
  const int tid = threadIdx.x;
  const int tx = tid & 15, ty = tid >> 4;
  const int  bc = blockIdx.x * 64;
  const long br = (long)blockIdx.y * 64;

  const int ar = tid >> 2, ak = (tid & 3) * 4;     // A-tile: 64 rows x 16 k
  const int bk = tid >> 4, bn = (tid & 15) * 4;    // B-tile: 16 k x 64 cols

  float acc[4][4] = {};

  for (int k0 = 0; k0 < CDIM; k0 += 16) {
    const TA* ap = A + (br + ar) * (long)CDIM + k0 + ak;
    float a0 = ldA(ap + 0), a1 = ldA(ap + 1), a2 = ldA(ap + 2), a3 = ldA(ap + 3);
    As[ak + 0][ar] = a0; As[ak + 1][ar] = a1;
    As[ak + 2][ar] = a2; As[ak + 3][ar] = a3;

    const int col = bc + bn;
    float4 bv;
    if (BMODE == 0) {
      bv = *(const float4*)(B0 + (size_t)(k0 + bk) * NCOLS + col);
    } else {
      if (col < 96) bv = *(const float4*)(B0 + (size_t)(k0 + bk) * 96 + col);
      else          bv = *(const float4*)(B1 + (size_t)(k0 + bk) * 32 + (col - 96));
    }
    *(float4*)&Bs[bk][bn] = bv;
    __syncthreads();

#pragma unroll
    for (int kk = 0; kk < 16; kk++) {
      float4 av = *(const float4*)&As[kk][ty * 4];
      float4 bw = *(const float4*)&Bs[kk][tx * 4];
      float aa[4] = {av.x, av.y, av.z, av.w};
      float bb[4] = {bw.x, bw.y, bw.z, bw.w};
#pragma unroll
      for (int i = 0; i < 4; i++)
#pragma unroll
        for (int j = 0; j < 4; j++) acc[i][j] += aa[i] * bb[j];
    }
    __syncthreads();
  }

#pragma unroll
  for (int i = 0; i < 4; i++) {
    long r = br + ty * 4 + i;
#pragma unroll
    for (int j = 0; j < 4; j++) {
      int c = bc + tx * 4 + j;
      float b = (BMODE == 0) ? bias0[c] : (c < 96 ? bias0[c] : bias1[c - 96]);
      stO(out + r * (long)NCOLS + c, acc[i][j] + b);
    }
  }
}

// One block per (n, q). Computes softmax(attn), sampling locations, 8-corner
// trilinear weights (premultiplied by attn), then gathers bf16 value and
// accumulates 768 output channels -> agg (bf16).
// value layout: value[(n*LIN + lin)*768 + h*96 + d]  (lin = (z*12+y)*12+x)
__global__ __launch_bounds__(256)
void sampler(const u16* __restrict__ value, const float* __restrict__ offatt,
             const float* __restrict__ refp, u16* __restrict__ agg)
{
  const int blk = blockIdx.x;          // n*LQ + q
  const int n   = blk / LQ;
  const int t   = threadIdx.x;

  __shared__ float s_off[128];
  __shared__ float s_attn[HH][PPTS];
  __shared__ int   s_cidx[HH][32];     // [h][p*8 + corner]
  __shared__ float s_cw[HH][32];       // weight * attn (0 if out of bounds)

  if (t < 128) s_off[t] = offatt[(size_t)blk * 128 + t];
  __syncthreads();

  if (t < 8) {  // per-head softmax over P=4
    float l[4], m = -1e30f;
#pragma unroll
    for (int p = 0; p < 4; p++) { l[p] = s_off[96 + t * 4 + p]; m = fmaxf(m, l[p]); }
    float s = 0.f;
#pragma unroll
    for (int p = 0; p < 4; p++) { l[p] = expf(l[p] - m); s += l[p]; }
    float inv = 1.f / s;
#pragma unroll
    for (int p = 0; p < 4; p++) s_attn[t][p] = l[p] * inv;
  }
  __syncthreads();

  if (t < 32) {  // one thread per (h,p): corner indices & weights
    const int h = t >> 2, p = t & 3;
    const float rx = refp[(size_t)blk * 3 + 0];
    const float ry = refp[(size_t)blk * 3 + 1];
    const float rz = refp[(size_t)blk * 3 + 2];
    // x = 12*loc - 0.5, loc = ref + off/12
    const float x = (float)NV * (rx + s_off[t * 3 + 0] * (1.f / NV)) - 0.5f;
    const float y = (float)NV * (ry + s_off[t * 3 + 1] * (1.f / NV)) - 0.5f;
    const float z = (float)NV * (rz + s_off[t * 3 + 2] * (1.f / NV)) - 0.5f;
    const float x0f = floorf(x), y0f = floorf(y), z0f = floorf(z);
    const int   x0 = (int)x0f, y0 = (int)y0f, z0 = (int)z0f;
    const float fx = x - x0f, fy = y - y0f, fz = z - z0f;
    const float aw = s_attn[h][p];
#pragma unroll
    for (int c = 0; c < 8; c++) {
      const int dx = c & 1, dy = (c >> 1) & 1, dz = c >> 2;
      const int xi = x0 + dx, yi = y0 + dy, zi = z0 + dz;
      const float w = (dx ? fx : 1.f - fx) * (dy ? fy : 1.f - fy) * (dz ? fz : 1.f - fz);
      const bool valid = (xi >= 0) & (xi < NV) & (yi >= 0) & (yi < NV) & (zi >= 0) & (zi < NV);
      const int xc = min(max(xi, 0), NV - 1);
      const int yc = min(max(yi, 0), NV - 1);
      const int zc = min(max(zi, 0), NV - 1);
      s_cidx[h][p * 8 + c] = (zc * NV + yc) * NV + xc;
      s_cw[h][p * 8 + c]   = valid ? w * aw : 0.f;
    }
  }
  __syncthreads();

  // 768 channels over 256 threads (3 each); gather 32 corners per head
  const u16* vn = value + (size_t)n * LIN * CDIM;
#pragma unroll
  for (int c = t; c < CDIM; c += 256) {
    const int h = c / DDIM, d = c % DDIM;
    const u16* vb = vn + h * DDIM + d;
    float acc = 0.f;
#pragma unroll 8
    for (int i = 0; i < 32; i++) {
      acc += s_cw[h][i] * bf2f(vb[(size_t)s_cidx[h][i] * CDIM]);
    }
    agg[(size_t)blk * CDIM + c] = f2bf(acc);
  }
}

extern "C" void kernel_launch(void* const* d_in, const int* in_sizes, int n_in,
                              void* d_out, int out_size, void* d_ws, size_t ws_size,
                              hipStream_t stream)
{
  const float* query = (const float*)d_in[0];
  const float* refp  = (const float*)d_in[1];
  const float* inpf  = (const float*)d_in[2];
  const float* w_val = (const float*)d_in[3];
  const float* b_val = (const float*)d_in[4];
  const float* w_off = (const float*)d_in[5];
  const float* b_off = (const float*)d_in[6];
  const float* w_att = (const float*)d_in[7];
  const float* b_att = (const float*)d_in[8];
  const float* w_out = (const float*)d_in[9];
  const float* b_out = (const float*)d_in[10];
  float* out = (float*)d_out;

  // workspace layout (bytes):
  //   value  bf16 13824*768*2 = 21,233,664
  //   offatt f32  32768*128*4 = 16,777,216
  //   agg    bf16 32768*768*2 = 50,331,648     total ~88.3 MB
  char* ws = (char*)d_ws;
  u16*   value  = (u16*)ws;
  float* offatt = (float*)(ws + 21233664);
  u16*   agg    = (u16*)(ws + 21233664 + 16777216);

  // K1: value = input_flatten @ w_val + b_val   (13824 x 768) -> bf16
  gemm64<float, u16, 0, CDIM>
      <<<dim3(CDIM / 64, (N_B * LIN) / 64), 256, 0, stream>>>(
          inpf, w_val, nullptr, b_val, nullptr, value);

  // K2: offatt = query @ [w_off | w_att] + [b_off | b_att]   (32768 x 128) -> f32
  gemm64<float, float, 1, 128>
      <<<dim3(128 / 64, (N_B * LQ) / 64), 256, 0, stream>>>(
          query, w_off, w_att, b_off, b_att, offatt);

  // K3: softmax + trilinear sampling + attn-weighted sum -> agg (32768 x 768) bf16
  sampler<<<N_B * LQ, 256, 0, stream>>>(value, offatt, refp, agg);

  // K4: out = agg @ w_out + b_out   (32768 x 768) -> f32
  gemm64<u16, float, 0, CDIM>
      <<<dim3(CDIM / 64, (N_B * LQ) / 64), 256, 0, stream>>>(
          agg, w_out, nullptr, b_out, nullptr, out);
}

// Round 2
// 461.921 us; speedup vs baseline: 2.3780x; 2.3780x over previous
//
#include <hip/hip_runtime.h>
#include <hip/hip_bf16.h>
#include <cstdint>
#include <cstddef>

// Problem constants: N=8, Lq=4096, C=768, H=8, P=4, D=96, 12^3 grid
#define N_B   8
#define LQ    4096
#define CDIM  768
#define HH    8
#define PPTS  4
#define DDIM  96
#define LIN   1728
#define NV    12

typedef unsigned short u16;
typedef unsigned int   u32;
typedef __attribute__((ext_vector_type(8))) short bf16x8;
typedef __attribute__((ext_vector_type(4))) float f32x4;

#define AS1 __attribute__((address_space(1)))
#define AS3 __attribute__((address_space(3)))

__device__ __forceinline__ float bf2f(u16 u) {
  unsigned x = ((unsigned)u) << 16;
  return __builtin_bit_cast(float, x);
}
__device__ __forceinline__ u16 f2bf(float f) {
  unsigned x = __builtin_bit_cast(unsigned, f);
  x += 0x7fffu + ((x >> 16) & 1u);   // round-to-nearest-even
  return (u16)(x >> 16);
}
__device__ __forceinline__ u32 pack2(float lo, float hi) {
  return (u32)f2bf(lo) | ((u32)f2bf(hi) << 16);
}
__device__ __forceinline__ void stO(float* p, float v) { *p = v; }
__device__ __forceinline__ void stO(u16* p, float v)   { *p = f2bf(v); }

// ---------------------------------------------------------------------------
// MFMA GEMM, m97 structure: 128x128 tile, BK=32, 256 threads = 4 waves (2x2),
// each wave 64x64 = 4x4 fragments of 16x16, K via mfma_f32_16x16x32_bf16.
// A: [M][768] (bf16 -> global_load_lds staging; f32 -> reg-stage + cvt).
// Bt: [NCOLS][768] bf16 (pre-transposed weights) -> global_load_lds staging.
// out[row][col] = sum_k A[row][k]*Bt[col][k] + bias[col].
// ---------------------------------------------------------------------------
template<typename TA, typename TOUT, int NCOLS>
__global__ __launch_bounds__(256)
void gemm_mfma(const TA* __restrict__ A, const u16* __restrict__ Bt,
               const float* __restrict__ bias, TOUT* __restrict__ out)
{
  __shared__ u16 As[128 * 32];   // [row][k], 64B rows
  __shared__ u16 Bs[128 * 32];   // [col][k]
  const int tid  = threadIdx.x;
  const int lane = tid & 63, wid = tid >> 6;
  const int wr = wid >> 1, wc = wid & 1;
  const long bm = (long)blockIdx.y * 128;
  const int  bn = blockIdx.x * 128;

  f32x4 acc[4][4] = {};

  for (int k0 = 0; k0 < CDIM; k0 += 32) {
    // ---- stage B (8 KB): 2 rounds x 4 waves x 1KB, LDS dest wave-uniform
#pragma unroll
    for (int r = 0; r < 2; ++r) {
      const int base = (r * 4 + wid) << 10;          // wave-uniform
      const int o    = base + lane * 16;             // this lane's bytes
      const int row  = o >> 6, kb = o & 63;
      const char* gp = (const char*)Bt + ((size_t)(bn + row) * CDIM + k0) * 2 + kb;
      __builtin_amdgcn_global_load_lds((const AS1 u32*)gp,
                                       (AS3 u32*)((char*)Bs + base), 16, 0, 0);
    }
    // ---- stage A
    if constexpr (sizeof(TA) == 2) {
#pragma unroll
      for (int r = 0; r < 2; ++r) {
        const int base = (r * 4 + wid) << 10;
        const int o    = base + lane * 16;
        const int row  = o >> 6, kb = o & 63;
        const char* gp = (const char*)A + ((size_t)(bm + row) * CDIM + k0) * 2 + kb;
        __builtin_amdgcn_global_load_lds((const AS1 u32*)gp,
                                         (AS3 u32*)((char*)As + base), 16, 0, 0);
      }
    } else {
      // f32 A: each thread covers 16 k-elems of one row; cvt -> 2x b128 writes
      const int row = tid >> 1, ke = (tid & 1) * 16;
      const float* gp = (const float*)A + (size_t)(bm + row) * CDIM + k0 + ke;
      float4 f0 = ((const float4*)gp)[0];
      float4 f1 = ((const float4*)gp)[1];
      float4 f2 = ((const float4*)gp)[2];
      float4 f3 = ((const float4*)gp)[3];
      u32 w0[4] = { pack2(f0.x, f0.y), pack2(f0.z, f0.w),
                    pack2(f1.x, f1.y), pack2(f1.z, f1.w) };
      u32 w1[4] = { pack2(f2.x, f2.y), pack2(f2.z, f2.w),
                    pack2(f3.x, f3.y), pack2(f3.z, f3.w) };
      *(uint4*)&As[row * 32 + ke]     = *(uint4*)w0;
      *(uint4*)&As[row * 32 + ke + 8] = *(uint4*)w1;
    }
    __syncthreads();

    // ---- fragments + 16 MFMA
    bf16x8 af[4], bfr[4];
    const int fr = lane & 15;
    const int kc = (lane >> 4) * 8;
#pragma unroll
    for (int i = 0; i < 4; ++i)
      af[i] = *(const bf16x8*)&As[(wr * 64 + i * 16 + fr) * 32 + kc];
#pragma unroll
    for (int j = 0; j < 4; ++j)
      bfr[j] = *(const bf16x8*)&Bs[(wc * 64 + j * 16 + fr) * 32 + kc];
#pragma unroll
    for (int i = 0; i < 4; ++i)
#pragma unroll
      for (int j = 0; j < 4; ++j)
        acc[i][j] = __builtin_amdgcn_mfma_f32_16x16x32_bf16(af[i], bfr[j], acc[i][j], 0, 0, 0);
    __syncthreads();
  }

  // ---- epilogue: C/D layout col=lane&15, row=(lane>>4)*4+reg
  const int crow0 = wr * 64 + (lane >> 4) * 4;
  const int ccol0 = wc * 64 + (lane & 15);
#pragma unroll
  for (int j = 0; j < 4; ++j) {
    const int col = bn + ccol0 + j * 16;
    const float bb = bias[col];
#pragma unroll
    for (int i = 0; i < 4; ++i) {
#pragma unroll
      for (int r = 0; r < 4; ++r) {
        const long row = bm + crow0 + i * 16 + r;
        stO(out + row * (long)NCOLS + col, acc[i][j][r] + bb);
      }
    }
  }
}

// ---------------------------------------------------------------------------
// Transpose-cast: src f32 [768][ncols] row-major -> dst bf16 [ncols][768]
// (written at dst row offset dstRowOff). 32x32 tiles, 256 threads.
// ---------------------------------------------------------------------------
__global__ __launch_bounds__(256)
void tcast(const float* __restrict__ src, u16* __restrict__ dst,
           int ncols, int dstRowOff)
{
  __shared__ float t[32][33];
  const int bx = blockIdx.x * 32;  // col in src
  const int by = blockIdx.y * 32;  // row (k) in src
  const int tx = threadIdx.x & 31, ty = threadIdx.x >> 5;
#pragma unroll
  for (int r = 0; r < 32; r += 8)
    t[ty + r][tx] = src[(size_t)(by + ty + r) * ncols + bx + tx];
  __syncthreads();
#pragma unroll
  for (int r = 0; r < 32; r += 8)
    dst[(size_t)(dstRowOff + bx + ty + r) * CDIM + by + tx] = f2bf(t[tx][ty + r]);
}

__global__ void bias_concat(const float* __restrict__ b_off,
                            const float* __restrict__ b_att,
                            float* __restrict__ dst)
{
  const int t = threadIdx.x;
  if (t < 96) dst[t] = b_off[t];
  else if (t < 128) dst[t] = b_att[t - 96];
}

// ---------------------------------------------------------------------------
// Sampler: one block per (n,q). softmax + trilinear weights, gather bf16 value.
// value layout: value[(n*LIN + lin)*768 + h*96 + d], lin = (z*12+y)*12+x
// ---------------------------------------------------------------------------
__global__ __launch_bounds__(256)
void sampler(const u16* __restrict__ value, const float* __restrict__ offatt,
             const float* __restrict__ refp, u16* __restrict__ agg)
{
  const int blk = blockIdx.x;          // n*LQ + q
  const int n   = blk / LQ;
  const int t   = threadIdx.x;

  __shared__ float s_off[128];
  __shared__ float s_attn[HH][PPTS];
  __shared__ int   s_cidx[HH][32];
  __shared__ float s_cw[HH][32];

  if (t < 128) s_off[t] = offatt[(size_t)blk * 128 + t];
  __syncthreads();

  if (t < 8) {
    float l[4], m = -1e30f;
#pragma unroll
    for (int p = 0; p < 4; p++) { l[p] = s_off[96 + t * 4 + p]; m = fmaxf(m, l[p]); }
    float s = 0.f;
#pragma unroll
    for (int p = 0; p < 4; p++) { l[p] = expf(l[p] - m); s += l[p]; }
    float inv = 1.f / s;
#pragma unroll
    for (int p = 0; p < 4; p++) s_attn[t][p] = l[p] * inv;
  }
  __syncthreads();

  if (t < 32) {
    const int h = t >> 2, p = t & 3;
    const float rx = refp[(size_t)blk * 3 + 0];
    const float ry = refp[(size_t)blk * 3 + 1];
    const float rz = refp[(size_t)blk * 3 + 2];
    const float x = (float)NV * (rx + s_off[t * 3 + 0] * (1.f / NV)) - 0.5f;
    const float y = (float)NV * (ry + s_off[t * 3 + 1] * (1.f / NV)) - 0.5f;
    const float z = (float)NV * (rz + s_off[t * 3 + 2] * (1.f / NV)) - 0.5f;
    const float x0f = floorf(x), y0f = floorf(y), z0f = floorf(z);
    const int   x0 = (int)x0f, y0 = (int)y0f, z0 = (int)z0f;
    const float fx = x - x0f, fy = y - y0f, fz = z - z0f;
    const float aw = s_attn[h][p];
#pragma unroll
    for (int c = 0; c < 8; c++) {
      const int dx = c & 1, dy = (c >> 1) & 1, dz = c >> 2;
      const int xi = x0 + dx, yi = y0 + dy, zi = z0 + dz;
      const float w = (dx ? fx : 1.f - fx) * (dy ? fy : 1.f - fy) * (dz ? fz : 1.f - fz);
      const bool valid = (xi >= 0) & (xi < NV) & (yi >= 0) & (yi < NV) & (zi >= 0) & (zi < NV);
      const int xc = min(max(xi, 0), NV - 1);
      const int yc = min(max(yi, 0), NV - 1);
      const int zc = min(max(zi, 0), NV - 1);
      s_cidx[h][p * 8 + c] = (zc * NV + yc) * NV + xc;
      s_cw[h][p * 8 + c]   = valid ? w * aw : 0.f;
    }
  }
  __syncthreads();

  const u16* vn = value + (size_t)n * LIN * CDIM;
#pragma unroll
  for (int c = t; c < CDIM; c += 256) {
    const int h = c / DDIM, d = c % DDIM;
    const u16* vb = vn + h * DDIM + d;
    float acc = 0.f;
#pragma unroll 8
    for (int i = 0; i < 32; i++) {
      acc += s_cw[h][i] * bf2f(vb[(size_t)s_cidx[h][i] * CDIM]);
    }
    agg[(size_t)blk * CDIM + c] = f2bf(acc);
  }
}

extern "C" void kernel_launch(void* const* d_in, const int* in_sizes, int n_in,
                              void* d_out, int out_size, void* d_ws, size_t ws_size,
                              hipStream_t stream)
{
  const float* query = (const float*)d_in[0];
  const float* refp  = (const float*)d_in[1];
  const float* inpf  = (const float*)d_in[2];
  const float* w_val = (const float*)d_in[3];
  const float* b_val = (const float*)d_in[4];
  const float* w_off = (const float*)d_in[5];
  const float* b_off = (const float*)d_in[6];
  const float* w_att = (const float*)d_in[7];
  const float* b_att = (const float*)d_in[8];
  const float* w_out = (const float*)d_in[9];
  const float* b_out = (const float*)d_in[10];
  float* out = (float*)d_out;

  // workspace layout (bytes), total ~90.9 MB:
  char* ws = (char*)d_ws;
  u16*   value   = (u16*)(ws + 0);                    // 21,233,664
  u16*   agg     = (u16*)(ws + 21233664);             // 50,331,648
  float* offatt  = (float*)(ws + 71565312);           // 16,777,216
  u16*   wT_val  = (u16*)(ws + 88342528);             //  1,179,648
  u16*   wT_out  = (u16*)(ws + 89522176);             //  1,179,648
  u16*   wT_oa   = (u16*)(ws + 90701824);             //    196,608
  float* bias_oa = (float*)(ws + 90898432);           //        512

  // prep: transpose-cast weights to bf16 [N][K]; concat off/att bias
  tcast<<<dim3(24, 24), 256, 0, stream>>>(w_val, wT_val, CDIM, 0);
  tcast<<<dim3(24, 24), 256, 0, stream>>>(w_out, wT_out, CDIM, 0);
  tcast<<<dim3(3, 24),  256, 0, stream>>>(w_off, wT_oa, 96, 0);
  tcast<<<dim3(1, 24),  256, 0, stream>>>(w_att, wT_oa, 32, 96);
  bias_concat<<<1, 128, 0, stream>>>(b_off, b_att, bias_oa);

  // K1: value = input_flatten @ w_val + b_val  (13824 x 768) -> bf16
  gemm_mfma<float, u16, CDIM>
      <<<dim3(6, (N_B * LIN) / 128), 256, 0, stream>>>(inpf, wT_val, b_val, value);

  // K2: offatt = query @ [w_off|w_att] + bias  (32768 x 128) -> f32
  gemm_mfma<float, float, 128>
      <<<dim3(1, (N_B * LQ) / 128), 256, 0, stream>>>(query, wT_oa, bias_oa, offatt);

  // K3: softmax + trilinear sampling -> agg (32768 x 768) bf16
  sampler<<<N_B * LQ, 256, 0, stream>>>(value, offatt, refp, agg);

  // K4: out = agg @ w_out + b_out  (32768 x 768) -> f32
  gemm_mfma<u16, float, CDIM>
      <<<dim3(6, (N_B * LQ) / 128), 256, 0, stream>>>(agg, wT_out, b_out, out);
}